// Round 9
// baseline (320.732 us; speedup 1.0000x reference)
//
#include <hip/hip_runtime.h>
#include <type_traits>

#define N_TOK 65536
#define K_CODE 8192
#define D_DIM 64

constexpr float DECAY = 0.9f;
constexpr float OMD = 0.1f;   // 1 - DECAY
constexpr float EPS = 1e-5f;

// ---- output layout (floats), per reference return order ----
constexpr int OUT_QE = 0;
constexpr int OUT_W  = 1;
constexpr int OUT_CS = 1 + K_CODE * D_DIM;
constexpr int OUT_EA = OUT_CS + K_CODE;

// ---- workspace layout (floats) ----
constexpr int WS_QE     = 0;
constexpr int WS_NSUM   = 1;
constexpr int WS_COUNTS = 16;
constexpr int WS_EMBSUM = WS_COUNTS + K_CODE;
constexpr int WS_WHI    = WS_EMBSUM + K_CODE * D_DIM;   // ushort[K*64] bf16 hi, XOR-swizzled
constexpr int WS_WLO    = WS_WHI + K_CODE * D_DIM / 2;  // ushort[K*64] bf16 lo, XOR-swizzled
constexpr int WS_CNP    = WS_WLO + K_CODE * D_DIM / 2;  // uint[K+64]: bf16(cn+64) hi|lo<<16 (+pad for DMA overread)
constexpr int WS_ZERO   = WS_WHI;                       // floats to memset

typedef __attribute__((ext_vector_type(16))) float floatx16;
typedef __attribute__((ext_vector_type(8)))  short short8;
typedef __attribute__((ext_vector_type(8)))  __bf16 bf16x8;

// SFINAE hedge: mfma bf16 builtin takes v8bf16 on newer clang, v8i16 on older.
template <typename T, typename = void> struct mfma_takes : std::false_type {};
template <typename T>
struct mfma_takes<T, std::void_t<decltype(__builtin_amdgcn_mfma_f32_32x32x16_bf16(
    std::declval<T>(), std::declval<T>(), std::declval<floatx16>(), 0, 0, 0))>>
    : std::true_type {};

__device__ __forceinline__ floatx16 MFMA(short8 a, short8 b, floatx16 c) {
  if constexpr (mfma_takes<bf16x8>::value) {
    return __builtin_amdgcn_mfma_f32_32x32x16_bf16(
        __builtin_bit_cast(bf16x8, a), __builtin_bit_cast(bf16x8, b), c, 0, 0, 0);
  } else {
    return __builtin_amdgcn_mfma_f32_32x32x16_bf16(a, b, c, 0, 0, 0);
  }
}

__device__ __forceinline__ unsigned short bf16rne(float x) {
  unsigned int u = __float_as_uint(x);
  return (unsigned short)((u + 0x7FFFu + ((u >> 16) & 1u)) >> 16);
}

// async global->LDS DMA (HW writes LDS at wave-uniform dst + lane*size)
__device__ __forceinline__ void gload_lds16(const unsigned short* g, unsigned short* l) {
#if defined(__has_builtin) && __has_builtin(__builtin_amdgcn_global_load_lds)
  typedef __attribute__((address_space(1))) void gvoid;
  typedef __attribute__((address_space(3))) void lvoid;
  __builtin_amdgcn_global_load_lds((gvoid*)g, (lvoid*)l, 16, 0, 0);
#else
  *(uint4*)l = *(const uint4*)g;
#endif
}
__device__ __forceinline__ void gload_lds4(const unsigned int* g, unsigned int* l) {
#if defined(__has_builtin) && __has_builtin(__builtin_amdgcn_global_load_lds)
  typedef __attribute__((address_space(1))) void gvoid;
  typedef __attribute__((address_space(3))) void lvoid;
  __builtin_amdgcn_global_load_lds((gvoid*)g, (lvoid*)l, 4, 0, 0);
#else
  *l = *g;
#endif
}

// ---------------------------------------------------------------------------
// Split W into bf16 hi/lo, stored XOR-SWIZZLED (granule g -> g^(k&7), stride
// 64 shorts) so the DMA's linear copy lands conflict-managed in LDS.
// Pack bf16 hi/lo of (||c||^2 + 64) per code (positive-key offset folded).
__global__ void vq_prep(const float* __restrict__ w, float* __restrict__ ws) {
  const int tid = threadIdx.x;
  const int d = tid & 63;
  const int k = blockIdx.x * 4 + (tid >> 6);
  const float v = w[(size_t)k * D_DIM + d];
  const unsigned short h = bf16rne(v);
  const float hf = __uint_as_float((unsigned int)h << 16);
  const unsigned short l = bf16rne(v - hf);
  unsigned short* whi = (unsigned short*)(ws + WS_WHI);
  unsigned short* wlo = (unsigned short*)(ws + WS_WLO);
  const int pos = k * D_DIM + (((d >> 3) ^ (k & 7)) * 8) + (d & 7);
  whi[pos] = h;
  wlo[pos] = l;
  float s = v * v;
#pragma unroll
  for (int m = 32; m >= 1; m >>= 1) s += __shfl_xor(s, m);
  if (d == 0) {
    const float cn64 = s + 64.0f;
    const unsigned short ch = bf16rne(cn64);
    const float chf = __uint_as_float((unsigned int)ch << 16);
    const unsigned short cl = bf16rne(cn64 - chf);
    ((unsigned int*)(ws + WS_CNP))[k] = (unsigned int)ch | ((unsigned int)cl << 16);
  }
}

// ---------------------------------------------------------------------------
// Barrier-free split-bf16 MFMA distance + argmin + segment-sum scatter.
// Block = 4 waves = 2 token-groups(64 tok) x 2 code-halves; 128 tokens/block.
// Grid 512, 2 blocks/CU. Each wave owns a PRIVATE double-buffered LDS stream
// (2 x 8 KB W + 2 x 256 B cn) that it alone DMAs (global_load_lds) and reads:
// no __syncthreads in the K-loop. Per 32-code stage: 9 DMA issues for s+1,
// `s_waitcnt vmcnt(9)` (keeps s+1 in flight - never drains to 0), ds_read
// stage s, 25 MFMAs (shared cn-fold head + 2x12 interleaved chains for the
// two 32-token A-sets). WAR on buffer reuse guarded by lgkmcnt(0) at stage
// top (own ds_reads long since landed). Epilogue 2 VALU/elem packed-key.
__global__ __launch_bounds__(256, 2) void vq_argmin(
    const float* __restrict__ z, float* __restrict__ ws)
{
  __shared__ __align__(16) unsigned short Wbuf[4][2][2][32 * 64]; // [wave][buf][plane]
  __shared__ unsigned int Wcn[4][2][64];                          // [wave][buf]
  __shared__ float mind_s[2][128];
  __shared__ int   tok_s[2][128];

  const int tid  = threadIdx.x;
  const int w    = tid >> 6;    // wave 0..3
  const int lane = tid & 63;
  const int m    = lane & 31;   // A row (token) / B col (code) in tile
  const int h    = lane >> 5;   // k-half selector
  const int hw   = w & 1;       // code half (4096 codes)
  const int tg   = w >> 1;      // token group (64 tokens)
  const int tb   = blockIdx.x * 128;

  const unsigned short* whiP = (const unsigned short*)(ws + WS_WHI) + (size_t)hw * 4096 * D_DIM;
  const unsigned short* wloP = (const unsigned short*)(ws + WS_WLO) + (size_t)hw * 4096 * D_DIM;
  const unsigned int*   cnpP = (const unsigned int*)(ws + WS_CNP) + hw * 4096;

  // ---- issue stage-s DMA into private buf b: 8x16B (W) + 1x4B (cn) = 9 vmem
  auto issueStage = [&](int s, int b) {
    const size_t roff = (size_t)s * (32 * D_DIM) + lane * 8;
#pragma unroll
    for (int i = 0; i < 4; ++i)
      gload_lds16(whiP + roff + i * 512, &Wbuf[w][b][0][i * 512]);
#pragma unroll
    for (int i = 0; i < 4; ++i)
      gload_lds16(wloP + roff + i * 512, &Wbuf[w][b][1][i * 512]);
    gload_lds4(cnpP + s * 32 + lane, &Wcn[w][b][0]);  // lanes 32-63 overread pad
  };

  issueStage(0, 0);   // overlaps with the A-split prologue below

  // ---- A fragments: bf16 hi/lo split of -2*z for 2 sets of 32 rows ----
  short8 ah[2][4], al[2][4];
  float znorm[2];
#pragma unroll
  for (int set = 0; set < 2; ++set) {
    const float* zrow = z + (size_t)(tb + tg * 64 + set * 32 + m) * D_DIM + 8 * h;
    float zn = 0.f;
#pragma unroll
    for (int s4 = 0; s4 < 4; ++s4) {
      const float4 v0 = *(const float4*)(zrow + 16 * s4);
      const float4 v1 = *(const float4*)(zrow + 16 * s4 + 4);
      const float vals[8] = {v0.x, v0.y, v0.z, v0.w, v1.x, v1.y, v1.z, v1.w};
#pragma unroll
      for (int j = 0; j < 8; ++j) {
        const float x = vals[j];
        zn += x * x;
        const float y = -2.0f * x;
        const unsigned short hb = bf16rne(y);
        const float hf = __uint_as_float((unsigned int)hb << 16);
        const unsigned short lb = bf16rne(y - hf);
        ah[set][s4][j] = (short)hb;
        al[set][s4][j] = (short)lb;
      }
    }
    zn += __shfl_xor(zn, 32);
    znorm[set] = zn;
  }

  // cn-fold head A operand: bf16 1.0 at k-slots 0,1 on h==0 lanes
  short8 acn;
  {
    uint4 ab = {0u, 0u, 0u, 0u};
    ab.x = (h == 0) ? 0x3F803F80u : 0u;
    acn = __builtin_bit_cast(short8, ab);
  }

  float kmin[2][16];
#pragma unroll
  for (int set = 0; set < 2; ++set)
#pragma unroll
    for (int r = 0; r < 16; ++r) kmin[set][r] = 3.4e38f;

  int xoff[4];
#pragma unroll
  for (int s4 = 0; s4 < 4; ++s4) xoff[s4] = ((2 * s4 + h) ^ (m & 7)) * 8;
  const int mrow = m * 64;
  const floatx16 kZero = {};

  for (int s = 0; s < 128; ++s) {
    const int b = s & 1;
    // WAR guard: my own ds_reads of buf b^1 (stage s-1) have drained
    asm volatile("s_waitcnt lgkmcnt(0)" ::: "memory");
    issueStage((s + 1) & 127, b ^ 1);          // uniform loop; s=127 wraps (unused)
    // RAW guard: allow the 9 just-issued to stay in flight; everything
    // older (stage s's 9 DMAs) must have landed. Never drains to 0.
    asm volatile("s_waitcnt vmcnt(9)" ::: "memory");

    short8 bh[4], bl[4];
#pragma unroll
    for (int s4 = 0; s4 < 4; ++s4) {
      bh[s4] = *(const short8*)&Wbuf[w][b][0][mrow + xoff[s4]];
      bl[s4] = *(const short8*)&Wbuf[w][b][1][mrow + xoff[s4]];
    }
    short8 bcn;
    {
      uint4 bb = {0u, 0u, 0u, 0u};
      bb.x = (h == 0) ? Wcn[w][b][m] : 0u;     // 2-way broadcast read, free
      bcn = __builtin_bit_cast(short8, bb);
    }

    const floatx16 head = MFMA(acn, bcn, kZero);   // ||c||^2 + 64 per col
    floatx16 a0, a1;
    a0 = MFMA(ah[0][0], bh[0], head);
    a1 = MFMA(ah[1][0], bh[0], head);
#pragma unroll
    for (int s4 = 1; s4 < 4; ++s4) {
      a0 = MFMA(ah[0][s4], bh[s4], a0);
      a1 = MFMA(ah[1][s4], bh[s4], a1);
    }
#pragma unroll
    for (int s4 = 0; s4 < 4; ++s4) {
      a0 = MFMA(al[0][s4], bh[s4], a0);
      a1 = MFMA(al[1][s4], bh[s4], a1);
    }
#pragma unroll
    for (int s4 = 0; s4 < 4; ++s4) {
      a0 = MFMA(ah[0][s4], bl[s4], a0);
      a1 = MFMA(ah[1][s4], bl[s4], a1);
    }

    // packed-key argmin: positive key, low byte := stage id (ascending =>
    // first-occurrence tie-break at 2^-9 relative precision)
#pragma unroll
    for (int r = 0; r < 16; ++r) {
      kmin[0][r] = fminf(kmin[0][r],
          __uint_as_float((__float_as_uint(a0[r]) & 0xFFFFFF00u) | (unsigned)s));
      kmin[1][r] = fminf(kmin[1][r],
          __uint_as_float((__float_as_uint(a1[r]) & 0xFFFFFF00u) | (unsigned)s));
    }
  }

  // ---- reduce over the 32 code-cols per row, carrying origin lane ----
#pragma unroll
  for (int set = 0; set < 2; ++set) {
#pragma unroll
    for (int r = 0; r < 16; ++r) {
      float kv = kmin[set][r];
      int mo = m;
#pragma unroll
      for (int mm = 1; mm < 32; mm <<= 1) {
        const float ov = __shfl_xor(kv, mm);
        const int   om = __shfl_xor(mo, mm);
        if (ov < kv || (ov == kv && om < mo)) { kv = ov; mo = om; }
      }
      // C/D layout: row = (r&3) + 8*(r>>2) + 4*h. One writer lane per row.
      const int mr = (r & 3) + 8 * (r >> 2) + 4 * h;
      if (m == mr) {
        const unsigned int kb = __float_as_uint(kv);
        const int t = tg * 64 + set * 32 + mr;
        tok_s[hw][t] = hw * 4096 + (int)(kb & 0xFFu) * 32 + mo;
        mind_s[hw][t] = __uint_as_float(kb & 0xFFFFFF00u) - 64.0f + znorm[set];
      }
    }
  }
  __syncthreads();   // the only block-wide barrier (also drains wrap-DMA)

  float* counts = ws + WS_COUNTS;
  float* embsum = ws + WS_EMBSUM;

  // merge code-halves (strict '<' keeps half0 on ties), qe partial + counts
  if (tid < 128) {
    const float d0 = mind_s[0][tid], d1 = mind_s[1][tid];
    const int   i0 = tok_s[0][tid],  i1 = tok_s[1][tid];
    const bool t1 = d1 < d0;
    const float dm = t1 ? d1 : d0;
    const int   im = t1 ? i1 : i0;
    tok_s[0][tid] = im;
    float qe = dm;
#pragma unroll
    for (int mm = 32; mm >= 1; mm >>= 1) qe += __shfl_xor(qe, mm);
    if ((tid & 63) == 0) atomicAdd(ws + WS_QE, qe);
    atomicAdd(&counts[im], 1.0f);
  }
  __syncthreads();

  // segment-sum of z: wave-coalesced atomics (64 consecutive floats/instr)
#pragma unroll 4
  for (int t = 0; t < 32; ++t) {
    const int row = w * 32 + t;
    const int tk = tok_s[0][row];
    const float zv = z[(size_t)(tb + row) * D_DIM + lane];
    atomicAdd(&embsum[(size_t)tk * D_DIM + lane], zv);
  }
}

// ---------------------------------------------------------------------------
__global__ void vq_finalize_cs(const float* __restrict__ cluster_size,
                               float* __restrict__ ws, float* __restrict__ out)
{
  const int k = blockIdx.x * 256 + threadIdx.x;
  const float ncs = cluster_size[k] * DECAY + OMD * ws[WS_COUNTS + k];
  out[OUT_CS + k] = ncs;
  float s = ncs;
#pragma unroll
  for (int m = 32; m >= 1; m >>= 1) s += __shfl_xor(s, m);
  __shared__ float part[4];
  if ((threadIdx.x & 63) == 0) part[threadIdx.x >> 6] = s;
  __syncthreads();
  if (threadIdx.x == 0) {
    atomicAdd(ws + WS_NSUM, part[0] + part[1] + part[2] + part[3]);
    if (blockIdx.x == 0) out[OUT_QE] = ws[WS_QE] * (1.0f / N_TOK);
  }
}

__global__ void vq_finalize_w(const float* __restrict__ embed_avg,
                              const float* __restrict__ ws, float* __restrict__ out)
{
  const int idx = blockIdx.x * 256 + threadIdx.x;
  const int k = idx >> 6;
  const float nea = embed_avg[idx] * DECAY + OMD * ws[WS_EMBSUM + idx];
  out[OUT_EA + idx] = nea;
  const float n = ws[WS_NSUM];
  const float ncs = out[OUT_CS + k];
  const float sm = (ncs + EPS) / (n + K_CODE * EPS) * n;
  out[OUT_W + idx] = nea / sm;
}

// ---------------------------------------------------------------------------
extern "C" void kernel_launch(void* const* d_in, const int* in_sizes, int n_in,
                              void* d_out, int out_size, void* d_ws, size_t ws_size,
                              hipStream_t stream) {
  const float* z  = (const float*)d_in[0];
  const float* w  = (const float*)d_in[1];
  const float* cs = (const float*)d_in[2];
  const float* ea = (const float*)d_in[3];
  float* out = (float*)d_out;
  float* ws  = (float*)d_ws;

  (void)hipMemsetAsync(d_ws, 0, (size_t)WS_ZERO * sizeof(float), stream);

  vq_prep<<<K_CODE / 4, 256, 0, stream>>>(w, ws);
  vq_argmin<<<N_TOK / 128, 256, 0, stream>>>(z, ws);
  vq_finalize_cs<<<K_CODE / 256, 256, 0, stream>>>(cs, ws, out);
  vq_finalize_w<<<K_CODE * D_DIM / 256, 256, 0, stream>>>(ea, ws, out);
}

// Round 10
// 303.156 us; speedup vs baseline: 1.0580x; 1.0580x over previous
//
#include <hip/hip_runtime.h>
#include <type_traits>

#define N_TOK 65536
#define K_CODE 8192
#define D_DIM 64

constexpr float DECAY = 0.9f;
constexpr float OMD = 0.1f;   // 1 - DECAY
constexpr float EPS = 1e-5f;

// ---- output layout (floats), per reference return order ----
constexpr int OUT_QE = 0;
constexpr int OUT_W  = 1;
constexpr int OUT_CS = 1 + K_CODE * D_DIM;
constexpr int OUT_EA = OUT_CS + K_CODE;

// ---- workspace layout (floats) ----
constexpr int WS_QE     = 0;
constexpr int WS_NSUM   = 1;
constexpr int WS_COUNTS = 16;
constexpr int WS_EMBSUM = WS_COUNTS + K_CODE;
constexpr int WS_WPK    = WS_EMBSUM + K_CODE * D_DIM;   // ushort[2*K*64] fragment-major + 8KB pad
constexpr int WS_CNP    = WS_WPK + (2 * K_CODE * D_DIM + 8192) / 2; // uint[K+64]
constexpr int WS_ZERO   = WS_WPK;                       // floats to memset

typedef __attribute__((ext_vector_type(16))) float floatx16;
typedef __attribute__((ext_vector_type(8)))  short short8;
typedef __attribute__((ext_vector_type(8)))  __bf16 bf16x8;

// SFINAE hedge: mfma bf16 builtin takes v8bf16 on newer clang, v8i16 on older.
template <typename T, typename = void> struct mfma_takes : std::false_type {};
template <typename T>
struct mfma_takes<T, std::void_t<decltype(__builtin_amdgcn_mfma_f32_32x32x16_bf16(
    std::declval<T>(), std::declval<T>(), std::declval<floatx16>(), 0, 0, 0))>>
    : std::true_type {};

__device__ __forceinline__ floatx16 MFMA(short8 a, short8 b, floatx16 c) {
  if constexpr (mfma_takes<bf16x8>::value) {
    return __builtin_amdgcn_mfma_f32_32x32x16_bf16(
        __builtin_bit_cast(bf16x8, a), __builtin_bit_cast(bf16x8, b), c, 0, 0, 0);
  } else {
    return __builtin_amdgcn_mfma_f32_32x32x16_bf16(a, b, c, 0, 0, 0);
  }
}

__device__ __forceinline__ unsigned short bf16rne(float x) {
  unsigned int u = __float_as_uint(x);
  return (unsigned short)((u + 0x7FFFu + ((u >> 16) & 1u)) >> 16);
}

// ---------------------------------------------------------------------------
// Build W in FRAGMENT-MAJOR layout: slot = (chunk*8 + plane*4 + s4), each
// slot = 512 shorts = one wave-load (lane = h*32+m reads shorts [lane*8..+8)
// = dims 16*s4+8*h+j of code chunk*32+m). Every K-loop load is a perfectly
// coalesced 1KB global_load_dwordx4 from L2 (W-split = 2MB, fits per-XCD L2).
// Also pack bf16 hi/lo of (||c||^2 + 64).
__global__ void vq_prep(const float* __restrict__ w, float* __restrict__ ws) {
  const int tid = threadIdx.x;
  const int d = tid & 63;
  const int k = blockIdx.x * 4 + (tid >> 6);
  const float v = w[(size_t)k * D_DIM + d];
  const unsigned short hbits = bf16rne(v);
  const float hf = __uint_as_float((unsigned int)hbits << 16);
  const unsigned short lbits = bf16rne(v - hf);
  unsigned short* wp = (unsigned short*)(ws + WS_WPK);
  const int c = k >> 5, m = k & 31;
  const int s4 = d >> 4, hh = (d >> 3) & 1, j = d & 7;
  const int lanepos = (hh * 32 + m) * 8 + j;
  wp[(size_t)(c * 8 + s4) * 512 + lanepos]     = hbits;   // hi plane slots 0..3
  wp[(size_t)(c * 8 + 4 + s4) * 512 + lanepos] = lbits;   // lo plane slots 4..7
  float s = v * v;
#pragma unroll
  for (int mm = 32; mm >= 1; mm >>= 1) s += __shfl_xor(s, mm);
  if (d == 0) {
    const float cn64 = s + 64.0f;
    const unsigned short ch = bf16rne(cn64);
    const float chf = __uint_as_float((unsigned int)ch << 16);
    const unsigned short cl = bf16rne(cn64 - chf);
    ((unsigned int*)(ws + WS_CNP))[k] = (unsigned int)ch | ((unsigned int)cl << 16);
  }
}

// ---------------------------------------------------------------------------
// LDS-free split-bf16 MFMA distance + argmin + segment-sum scatter.
// Block = 4 waves x 64 tokens; wave = 2 A-sets(32 tok) x one 2048-code
// quarter. Grid 1024. B streams L2->VGPR via coalesced 1KB loads, software-
// pipelined at s4-granule distance 2 (2 ping-pong reg pairs); compiler emits
// exact vmcnt waits (never drains to 0). No LDS, no DMA, no K-loop barriers.
// Per 32-code stage: cn-fold head MFMA + 4 s4-groups x 6 MFMAs (2 chains).
// Epilogue 2 VALU/elem packed-key (low byte = stage id: first-occurrence
// tie-break at 2^-9 relative precision).
__global__ __launch_bounds__(256, 3) void vq_argmin(
    const float* __restrict__ z, float* __restrict__ ws)
{
  __shared__ float mind_s[4][64];
  __shared__ int   tok_s[4][64];

  const int tid  = threadIdx.x;
  const int cq   = tid >> 6;    // wave = code quarter 0..3
  const int lane = tid & 63;
  const int m    = lane & 31;   // A row (token) / B col (code) in tile
  const int h    = lane >> 5;   // k-half selector
  const int tb   = blockIdx.x * 64;

  const unsigned short* wp = (const unsigned short*)(ws + WS_WPK);
  const unsigned int* cnp = (const unsigned int*)(ws + WS_CNP);

  // ---- A fragments: bf16 hi/lo split of -2*z for 2 sets of 32 rows ----
  short8 ah[2][4], al[2][4];
  float znorm[2];
#pragma unroll
  for (int set = 0; set < 2; ++set) {
    const float* zrow = z + (size_t)(tb + set * 32 + m) * D_DIM + 8 * h;
    float zn = 0.f;
#pragma unroll
    for (int s4 = 0; s4 < 4; ++s4) {
      const float4 v0 = *(const float4*)(zrow + 16 * s4);
      const float4 v1 = *(const float4*)(zrow + 16 * s4 + 4);
      const float vals[8] = {v0.x, v0.y, v0.z, v0.w, v1.x, v1.y, v1.z, v1.w};
#pragma unroll
      for (int j = 0; j < 8; ++j) {
        const float x = vals[j];
        zn += x * x;
        const float y = -2.0f * x;
        const unsigned short hb = bf16rne(y);
        const float hf = __uint_as_float((unsigned int)hb << 16);
        const unsigned short lb = bf16rne(y - hf);
        ah[set][s4][j] = (short)hb;
        al[set][s4][j] = (short)lb;
      }
    }
    zn += __shfl_xor(zn, 32);
    znorm[set] = zn;
  }

  // cn-fold head A operand: bf16 1.0 at k-slots 0,1 on h==0 lanes
  short8 acn;
  {
    uint4 ab = {0u, 0u, 0u, 0u};
    ab.x = (h == 0) ? 0x3F803F80u : 0u;
    acn = __builtin_bit_cast(short8, ab);
  }

  float kmin[2][16];
#pragma unroll
  for (int set = 0; set < 2; ++set)
#pragma unroll
    for (int r = 0; r < 16; ++r) kmin[set][r] = 3.4e38f;

  // ---- B pipeline: slot s -> 1KB coalesced load, lane offset lane*8 ----
  const unsigned short* wlane = wp + lane * 8;
  auto LD = [&](int slot) -> short8 {
    return *(const short8*)(wlane + (size_t)slot * 512);
  };

  const int c0 = cq * 64;              // first 32-code chunk of this quarter
  short8 bufh[2], bufl[2];
  bufh[0] = LD(c0 * 8 + 0); bufl[0] = LD(c0 * 8 + 4);   // (s=0, s4=0)
  bufh[1] = LD(c0 * 8 + 1); bufl[1] = LD(c0 * 8 + 5);   // (s=0, s4=1)
  unsigned int cnq = cnp[cq * 2048 + m];

  const floatx16 kZero = {};

  for (int s = 0; s < 64; ++s) {
    const int cslot = (c0 + s) * 8;
    const unsigned int cn_cur = cnq;
    cnq = cnp[cq * 2048 + (s + 1) * 32 + m];   // prefetch next (pad at end)

    short8 bcn;
    {
      uint4 bb = {0u, 0u, 0u, 0u};
      bb.x = (h == 0) ? cn_cur : 0u;
      bcn = __builtin_bit_cast(short8, bb);
    }
    const floatx16 head = MFMA(acn, bcn, kZero);   // ||c||^2 + 64 per col
    floatx16 a0 = head, a1 = head;

    // s4-groups: use parity buffer, prefetch granule t+2 into same parity.
    // (s4=0,1 -> prefetch (s,2),(s,3); s4=2,3 -> prefetch (s+1,0),(s+1,1))
#pragma unroll
    for (int s4 = 0; s4 < 4; ++s4) {
      const int p = s4 & 1;
      const short8 bh = bufh[p];
      const short8 bl = bufl[p];
      const int nslot = cslot + s4 + 2 + ((s4 >> 1) * 4);  // +2,+3,+8,+9
      bufh[p] = LD(nslot);                                  // hi: slots+0
      bufl[p] = LD(nslot + 4);                              // lo: slots+4
      a0 = MFMA(ah[0][s4], bh, a0);
      a1 = MFMA(ah[1][s4], bh, a1);
      a0 = MFMA(al[0][s4], bh, a0);
      a1 = MFMA(al[1][s4], bh, a1);
      a0 = MFMA(ah[0][s4], bl, a0);
      a1 = MFMA(ah[1][s4], bl, a1);
    }

    // packed-key argmin: positive key, low byte := stage id
#pragma unroll
    for (int r = 0; r < 16; ++r) {
      kmin[0][r] = fminf(kmin[0][r],
          __uint_as_float((__float_as_uint(a0[r]) & 0xFFFFFF00u) | (unsigned)s));
      kmin[1][r] = fminf(kmin[1][r],
          __uint_as_float((__float_as_uint(a1[r]) & 0xFFFFFF00u) | (unsigned)s));
    }
  }

  // ---- reduce over the 32 code-cols per row, carrying origin lane ----
#pragma unroll
  for (int set = 0; set < 2; ++set) {
#pragma unroll
    for (int r = 0; r < 16; ++r) {
      float kv = kmin[set][r];
      int mo = m;
#pragma unroll
      for (int mm = 1; mm < 32; mm <<= 1) {
        const float ov = __shfl_xor(kv, mm);
        const int   om = __shfl_xor(mo, mm);
        if (ov < kv || (ov == kv && om < mo)) { kv = ov; mo = om; }
      }
      // C/D layout: row = (r&3) + 8*(r>>2) + 4*h. One writer lane per row.
      const int mr = (r & 3) + 8 * (r >> 2) + 4 * h;
      if (m == mr) {
        const unsigned int kb = __float_as_uint(kv);
        const int t = set * 32 + mr;
        tok_s[cq][t] = cq * 2048 + (int)(kb & 0xFFu) * 32 + mo;
        mind_s[cq][t] = __uint_as_float(kb & 0xFFFFFF00u) - 64.0f + znorm[set];
      }
    }
  }
  __syncthreads();

  float* counts = ws + WS_COUNTS;
  float* embsum = ws + WS_EMBSUM;

  // merge 4 code-quarters (ascending q + strict '<' = first-index ties),
  // then qe partial + counts
  if (tid < 64) {
    float dm = mind_s[0][tid];
    int   im = tok_s[0][tid];
#pragma unroll
    for (int q = 1; q < 4; ++q) {
      const float dq = mind_s[q][tid];
      const int   iq = tok_s[q][tid];
      if (dq < dm) { dm = dq; im = iq; }
    }
    tok_s[0][tid] = im;
    float qe = dm;
#pragma unroll
    for (int mm = 32; mm >= 1; mm >>= 1) qe += __shfl_xor(qe, mm);
    if (tid == 0) atomicAdd(ws + WS_QE, qe);
    atomicAdd(&counts[im], 1.0f);
  }
  __syncthreads();

  // segment-sum of z: wave-coalesced atomics (64 consecutive floats/instr)
#pragma unroll 4
  for (int t = 0; t < 16; ++t) {
    const int row = cq * 16 + t;
    const int tk = tok_s[0][row];
    const float zv = z[(size_t)(tb + row) * D_DIM + lane];
    atomicAdd(&embsum[(size_t)tk * D_DIM + lane], zv);
  }
}

// ---------------------------------------------------------------------------
__global__ void vq_finalize_cs(const float* __restrict__ cluster_size,
                               float* __restrict__ ws, float* __restrict__ out)
{
  const int k = blockIdx.x * 256 + threadIdx.x;
  const float ncs = cluster_size[k] * DECAY + OMD * ws[WS_COUNTS + k];
  out[OUT_CS + k] = ncs;
  float s = ncs;
#pragma unroll
  for (int m = 32; m >= 1; m >>= 1) s += __shfl_xor(s, m);
  __shared__ float part[4];
  if ((threadIdx.x & 63) == 0) part[threadIdx.x >> 6] = s;
  __syncthreads();
  if (threadIdx.x == 0) {
    atomicAdd(ws + WS_NSUM, part[0] + part[1] + part[2] + part[3]);
    if (blockIdx.x == 0) out[OUT_QE] = ws[WS_QE] * (1.0f / N_TOK);
  }
}

__global__ void vq_finalize_w(const float* __restrict__ embed_avg,
                              const float* __restrict__ ws, float* __restrict__ out)
{
  const int idx = blockIdx.x * 256 + threadIdx.x;
  const int k = idx >> 6;
  const float nea = embed_avg[idx] * DECAY + OMD * ws[WS_EMBSUM + idx];
  out[OUT_EA + idx] = nea;
  const float n = ws[WS_NSUM];
  const float ncs = out[OUT_CS + k];
  const float sm = (ncs + EPS) / (n + K_CODE * EPS) * n;
  out[OUT_W + idx] = nea / sm;
}

// ---------------------------------------------------------------------------
extern "C" void kernel_launch(void* const* d_in, const int* in_sizes, int n_in,
                              void* d_out, int out_size, void* d_ws, size_t ws_size,
                              hipStream_t stream) {
  const float* z  = (const float*)d_in[0];
  const float* w  = (const float*)d_in[1];
  const float* cs = (const float*)d_in[2];
  const float* ea = (const float*)d_in[3];
  float* out = (float*)d_out;
  float* ws  = (float*)d_ws;

  (void)hipMemsetAsync(d_ws, 0, (size_t)WS_ZERO * sizeof(float), stream);

  vq_prep<<<K_CODE / 4, 256, 0, stream>>>(w, ws);
  vq_argmin<<<N_TOK / 64, 256, 0, stream>>>(z, ws);
  vq_finalize_cs<<<K_CODE / 256, 256, 0, stream>>>(cs, ws, out);
  vq_finalize_w<<<K_CODE * D_DIM / 256, 256, 0, stream>>>(ea, ws, out);
}